// Round 2
// baseline (21092.978 us; speedup 1.0000x reference)
//
#include <hip/hip_runtime.h>
#include <hip/hip_bf16.h>
#include <math.h>

// ============================================================================
// ResponseFilter — round 1: slim-workspace fp32 pipeline (bf16 QKV/hidden).
//
// Round-0 post-mortem: core-dump abort == GPU page fault; ws layout needed
// 421 MB (fp32 QKV 302 MB). This round fits peak ws in ~146 MB:
//   - X (residual, fp32, 100.7 MB) lives in d_out's new_emb region (dead
//     before maskout/newemb run).
//   - QKV + FFN-hidden stored bf16 (RNE), overlaid in one ws region (151 MB).
//   - attn output O aliases QKV's Q columns (each block writes exactly the
//     cells only it reads -> race-free).
//   - Z (fp32, 16.8 MB) overlays the same region between enc and dec.
// Residual stream / LN / softmax stats / scores all fp32 -> argmin ordering
// robust (est. score noise ~0.05 vs gaps O(0.1-0.5)).
//
// ws (bytes): meta ints + bias2 + emean + Sv = 1,714,176 B, then bf16 region
// 150,994,944 B  -> total 152,709,120 B (~146 MB).
// ============================================================================

#define B_  16
#define T_  32
#define L_  64
#define D_  768
#define H_  12
#define F_  2048
#define ZR_ 100
#define ZP_ 128
#define NP_ 512
#define EPS_ 1e-5f

// meta int offsets (d_ws as int*)
#define MI_NTOT  0
#define MI_NRESP 8
#define MI_OFF   32
#define MI_BIDX  64
#define MI_TIDX  576
#define MI_NODE  1088

// ws float offsets
#define WS_BIAS2 2048
#define WS_EMEAN 34816
#define WS_S     428032
#define WS_BIG   428544   // bf16 QKV/hidden region (as ushort*), fp32 Z overlay

// d_out float offsets (flat tuple: oh[512], ext_mask[32768], n_ext_adv[1],
// new_tree_lens[16], new_emb[25165824], new_msk[32768])
#define OUT_OH   0
#define OUT_EXT  512
#define OUT_NEA  33280
#define OUT_NTL  33281
#define OUT_NEMB 33297
#define OUT_NMSK 25199121
#define OUT_XSCR 33300   // fp32 X scratch (16B aligned), NP_*64*768 floats

__device__ inline float bf2f(unsigned s) {
  return __uint_as_float((s & 0xffffu) << 16);
}
__device__ inline unsigned short f2bf(float x) {
  unsigned u = __float_as_uint(x);
  u += 0x7fffu + ((u >> 16) & 1u);      // round-to-nearest-even
  return (unsigned short)(u >> 16);
}
__device__ inline unsigned pack2(float a, float b) {
  return (unsigned)f2bf(a) | ((unsigned)f2bf(b) << 16);
}

// ---------------------------------------------------------------------------
__global__ void meta_kernel(const int* __restrict__ tl, int* __restrict__ mi) {
  if (threadIdx.x != 0) return;
  int off = 0;
  for (int b = 0; b < B_; b++) {
    int nr = tl[b] - 1;
    mi[MI_NRESP + b] = nr;
    mi[MI_OFF + b] = off;
    off += nr;
  }
  mi[MI_NTOT] = off;
  for (int j = 0; j < NP_; j++) {
    int b = -1, t = 0;
    if (j < off) {
      b = 0;
      while (b + 1 < B_ && j >= mi[MI_OFF + b + 1]) b++;
      t = j - mi[MI_OFF + b] + 1;
    }
    mi[MI_BIDX + j] = b;
    mi[MI_TIDX + j] = t;
  }
}

// ---------------------------------------------------------------------------
// X[j,l,:] = reply embedding (zero for padded j); bias2[j*64+l] = mask or -1e30
__global__ __launch_bounds__(192) void gather_kernel(
    const float* __restrict__ emb, const float* __restrict__ am,
    const int* __restrict__ mi, float* __restrict__ X, float* __restrict__ bias2) {
  const int blk = blockIdx.x;          // j*64 + l
  const int j = blk >> 6, l = blk & 63;
  const int ntot = mi[MI_NTOT];
  const int t = threadIdx.x;
  float4 v = make_float4(0.f, 0.f, 0.f, 0.f);
  if (j < ntot) {
    const int b = mi[MI_BIDX + j], tt = mi[MI_TIDX + j];
    v = ((const float4*)(emb + (size_t)((b * T_ + tt) * L_ + l) * D_))[t];
    if (t == 0) bias2[blk] = am[(b * T_ + tt) * L_ + l];
  } else {
    if (t == 0) bias2[blk] = -1e30f;
  }
  ((float4*)(X + (size_t)blk * D_))[t] = v;
}

// ---------------------------------------------------------------------------
__global__ __launch_bounds__(256) void emean_kernel(const float* __restrict__ X,
                                                    float* __restrict__ em) {
  const int j = blockIdx.x;
  int d = threadIdx.x;
  for (int c = 0; c < 3; c++, d += 256) {
    const float* p = X + (size_t)j * L_ * D_ + d;
    float s = 0.f;
    for (int l = 0; l < L_; l++) s += p[l * D_];
    em[j * D_ + d] = s * (1.f / 64.f);
  }
}

// ---------------------------------------------------------------------------
__device__ inline float blockSum256(float v, float* red) {
  #pragma unroll
  for (int o = 32; o > 0; o >>= 1) v += __shfl_down(v, o);
  const int lane = threadIdx.x & 63, wid = threadIdx.x >> 6;
  __syncthreads();
  if (lane == 0) red[wid] = v;
  __syncthreads();
  return red[0] + red[1] + red[2] + red[3];
}

// in-place LN over D=768 rows; skips padded rows
__global__ __launch_bounds__(256) void ln_kernel(float* __restrict__ X,
                                                 const float* __restrict__ g,
                                                 const float* __restrict__ bb,
                                                 const int* __restrict__ mi) {
  const int row = blockIdx.x;
  if (row >= mi[MI_NTOT] * L_) return;
  float* p = X + (size_t)row * D_;
  const int t = threadIdx.x;
  __shared__ float red[4];
  float v0 = p[t], v1 = p[t + 256], v2 = p[t + 512];
  float s = blockSum256(v0 + v1 + v2, red);
  float m = s * (1.f / 768.f);
  float d0 = v0 - m, d1 = v1 - m, d2 = v2 - m;
  float q = blockSum256(d0 * d0 + d1 * d1 + d2 * d2, red);
  float r = rsqrtf(q * (1.f / 768.f) + EPS_);
  p[t]       = d0 * r * g[t]       + bb[t];
  p[t + 256] = d1 * r * g[t + 256] + bb[t + 256];
  p[t + 512] = d2 * r * g[t + 512] + bb[t + 512];
}

// ---------------------------------------------------------------------------
// C[M,N] = [dst +] act(A[M,K] @ W[N,K]^T + bias); tile 64x64xK16, 256 thr, 4x4.
// AT/CT: 0 = fp32, 1 = bf16 (A strided by lda elements; C by ldc elements).
// W fp32, scalar guarded loads (handles K=100/N=100 ragged cases).
// Row tile == one response j -> skip if j >= Ntot.
template <int ACT, bool ADD, int AT, int CT>
__global__ __launch_bounds__(256) void gemm_kernel(
    const void* __restrict__ Av, int lda, int kloop,
    const float* __restrict__ W, int kw, int nreal,
    const float* __restrict__ bias,
    void* __restrict__ Cv, int ldc,
    const int* __restrict__ mi) {
  if ((int)blockIdx.x >= mi[MI_NTOT]) return;
  __shared__ float As[16][68];
  __shared__ float Ws[16][68];
  const int t = threadIdx.x;
  const int tx = t & 15, ty = t >> 4;
  const int lrow = t >> 2, lkg = (t & 3) * 4;
  const size_t row0 = (size_t)blockIdx.x * 64;
  const int col0 = blockIdx.y * 64;
  float acc[4][4] = {};
  for (int k0 = 0; k0 < kloop; k0 += 16) {
    float a4[4];
    if (AT == 0) {
      float4 av = *(const float4*)((const float*)Av + (row0 + lrow) * (size_t)lda + k0 + lkg);
      a4[0] = av.x; a4[1] = av.y; a4[2] = av.z; a4[3] = av.w;
    } else {
      uint2 u = *(const uint2*)((const unsigned short*)Av + (row0 + lrow) * (size_t)lda + k0 + lkg);
      a4[0] = bf2f(u.x); a4[1] = bf2f(u.x >> 16);
      a4[2] = bf2f(u.y); a4[3] = bf2f(u.y >> 16);
    }
    float wv[4];
    const int wn = col0 + lrow;
    #pragma unroll
    for (int i = 0; i < 4; i++) {
      const int k = k0 + lkg + i;
      wv[i] = (wn < nreal && k < kw) ? W[(size_t)wn * kw + k] : 0.f;
    }
    __syncthreads();
    As[lkg + 0][lrow] = a4[0]; As[lkg + 1][lrow] = a4[1];
    As[lkg + 2][lrow] = a4[2]; As[lkg + 3][lrow] = a4[3];
    Ws[lkg + 0][lrow] = wv[0]; Ws[lkg + 1][lrow] = wv[1];
    Ws[lkg + 2][lrow] = wv[2]; Ws[lkg + 3][lrow] = wv[3];
    __syncthreads();
    #pragma unroll
    for (int kk = 0; kk < 16; kk++) {
      float4 av4 = *(const float4*)(&As[kk][ty * 4]);
      float4 wv4 = *(const float4*)(&Ws[kk][tx * 4]);
      float aa[4] = {av4.x, av4.y, av4.z, av4.w};
      float ww[4] = {wv4.x, wv4.y, wv4.z, wv4.w};
      #pragma unroll
      for (int i = 0; i < 4; i++)
        #pragma unroll
        for (int j = 0; j < 4; j++) acc[i][j] += aa[i] * ww[j];
    }
  }
  const int n0 = col0 + tx * 4;
  float bv[4];
  #pragma unroll
  for (int j = 0; j < 4; j++) bv[j] = (n0 + j < nreal) ? bias[n0 + j] : 0.f;
  #pragma unroll
  for (int i = 0; i < 4; i++) {
    float v[4];
    #pragma unroll
    for (int j = 0; j < 4; j++) {
      float x = acc[i][j] + bv[j];
      if (ACT == 1) x = fmaxf(x, 0.f);
      if (ACT == 2) x = tanhf(x);
      v[j] = x;
    }
    if (CT == 0) {
      float* cp = (float*)Cv + (row0 + ty * 4 + i) * (size_t)ldc + n0;
      float4 outv = make_float4(v[0], v[1], v[2], v[3]);
      if (ADD) {
        float4 old = *(const float4*)cp;
        outv.x += old.x; outv.y += old.y; outv.z += old.z; outv.w += old.w;
      }
      *(float4*)cp = outv;
    } else {
      unsigned short* cp = (unsigned short*)Cv + (row0 + ty * 4 + i) * (size_t)ldc + n0;
      uint2 pk; pk.x = pack2(v[0], v[1]); pk.y = pack2(v[2], v[3]);
      *(uint2*)cp = pk;
    }
  }
}

// ---------------------------------------------------------------------------
// Attention over the response dim per (l, h): block = (64-row n-tile, l, h),
// flash-style online softmax over 8 m-tiles of 64. QKV bf16 (stride 2304).
// Output O (bf16) written into QKV's Q columns: each block writes exactly the
// cells only it reads -> race-free aliasing.
__global__ __launch_bounds__(256) void attn_kernel(
    unsigned short* __restrict__ QKV, const float* __restrict__ bias2,
    const int* __restrict__ mi) {
  const int ntot = mi[MI_NTOT];
  const int nt = blockIdx.x, l = blockIdx.y, h = blockIdx.z;
  if (nt * 64 >= ntot) return;
  __shared__ float Qs[64][68];
  __shared__ float KVs[64][68];
  __shared__ float Ps[64][68];
  const int t = threadIdx.x;
  const int tx = t & 15, ty = t >> 4;
  const int lrow = t >> 2, lf = (t & 3) * 4;
  // Q load (transposed [d][n])
  #pragma unroll
  for (int c = 0; c < 4; c++) {
    const int d0 = lf + c * 16;
    uint2 q = *(const uint2*)(QKV + (size_t)((nt * 64 + lrow) * L_ + l) * 2304 + h * 64 + d0);
    Qs[d0 + 0][lrow] = bf2f(q.x); Qs[d0 + 1][lrow] = bf2f(q.x >> 16);
    Qs[d0 + 2][lrow] = bf2f(q.y); Qs[d0 + 3][lrow] = bf2f(q.y >> 16);
  }
  float runmax[4], runsum[4], oa[4][4];
  #pragma unroll
  for (int i = 0; i < 4; i++) {
    runmax[i] = -3.0e38f; runsum[i] = 0.f;
    #pragma unroll
    for (int j = 0; j < 4; j++) oa[i][j] = 0.f;
  }
  __syncthreads();
  for (int mt = 0; mt < 8; mt++) {
    // K load (transposed [d][m])
    #pragma unroll
    for (int c = 0; c < 4; c++) {
      const int d0 = lf + c * 16;
      uint2 k = *(const uint2*)(QKV + (size_t)((mt * 64 + lrow) * L_ + l) * 2304 + 768 + h * 64 + d0);
      KVs[d0 + 0][lrow] = bf2f(k.x); KVs[d0 + 1][lrow] = bf2f(k.x >> 16);
      KVs[d0 + 2][lrow] = bf2f(k.y); KVs[d0 + 3][lrow] = bf2f(k.y >> 16);
    }
    __syncthreads();
    float sv[4][4] = {};
    #pragma unroll 8
    for (int kk = 0; kk < 64; kk++) {
      float4 q4 = *(const float4*)(&Qs[kk][ty * 4]);
      float4 k4 = *(const float4*)(&KVs[kk][tx * 4]);
      float qa[4] = {q4.x, q4.y, q4.z, q4.w};
      float ka[4] = {k4.x, k4.y, k4.z, k4.w};
      #pragma unroll
      for (int i = 0; i < 4; i++)
        #pragma unroll
        for (int j = 0; j < 4; j++) sv[i][j] += qa[i] * ka[j];
    }
    float bj[4];
    #pragma unroll
    for (int j = 0; j < 4; j++) bj[j] = bias2[(mt * 64 + tx * 4 + j) * 64 + l];
    float tmax[4], tsum[4];
    #pragma unroll
    for (int i = 0; i < 4; i++) {
      #pragma unroll
      for (int j = 0; j < 4; j++) sv[i][j] = sv[i][j] * 0.125f + bj[j];
      tmax[i] = fmaxf(fmaxf(sv[i][0], sv[i][1]), fmaxf(sv[i][2], sv[i][3]));
    }
    #pragma unroll
    for (int o2 = 1; o2 < 16; o2 <<= 1)
      #pragma unroll
      for (int i = 0; i < 4; i++) tmax[i] = fmaxf(tmax[i], __shfl_xor(tmax[i], o2));
    #pragma unroll
    for (int i = 0; i < 4; i++) {
      const float nmax = fmaxf(runmax[i], tmax[i]);
      const float alpha = __expf(runmax[i] - nmax);
      runmax[i] = nmax;
      float s0 = 0.f;
      #pragma unroll
      for (int j = 0; j < 4; j++) { sv[i][j] = __expf(sv[i][j] - nmax); s0 += sv[i][j]; }
      tsum[i] = s0;
      #pragma unroll
      for (int j = 0; j < 4; j++) oa[i][j] *= alpha;
      runsum[i] *= alpha;
    }
    #pragma unroll
    for (int o2 = 1; o2 < 16; o2 <<= 1)
      #pragma unroll
      for (int i = 0; i < 4; i++) tsum[i] += __shfl_xor(tsum[i], o2);
    #pragma unroll
    for (int i = 0; i < 4; i++) runsum[i] += tsum[i];
    __syncthreads();
    // P -> LDS; V -> LDS (natural [m][d], reuses K slot)
    #pragma unroll
    for (int i = 0; i < 4; i++)
      *(float4*)(&Ps[ty * 4 + i][tx * 4]) = make_float4(sv[i][0], sv[i][1], sv[i][2], sv[i][3]);
    #pragma unroll
    for (int c = 0; c < 4; c++) {
      const int d0 = lf + c * 16;
      uint2 v = *(const uint2*)(QKV + (size_t)((mt * 64 + lrow) * L_ + l) * 2304 + 1536 + h * 64 + d0);
      KVs[lrow][d0 + 0] = bf2f(v.x); KVs[lrow][d0 + 1] = bf2f(v.x >> 16);
      KVs[lrow][d0 + 2] = bf2f(v.y); KVs[lrow][d0 + 3] = bf2f(v.y >> 16);
    }
    __syncthreads();
    #pragma unroll 4
    for (int m4 = 0; m4 < 16; m4++) {
      float4 pr[4];
      #pragma unroll
      for (int i = 0; i < 4; i++) pr[i] = *(const float4*)(&Ps[ty * 4 + i][m4 * 4]);
      #pragma unroll
      for (int c = 0; c < 4; c++) {
        float4 v4 = *(const float4*)(&KVs[m4 * 4 + c][tx * 4]);
        float va[4] = {v4.x, v4.y, v4.z, v4.w};
        float pc[4];
        #pragma unroll
        for (int i = 0; i < 4; i++) pc[i] = ((const float*)&pr[i])[c];
        #pragma unroll
        for (int i = 0; i < 4; i++)
          #pragma unroll
          for (int j = 0; j < 4; j++) oa[i][j] += pc[i] * va[j];
      }
    }
    __syncthreads();
  }
  #pragma unroll
  for (int i = 0; i < 4; i++) {
    const float inv = 1.f / runsum[i];
    unsigned short* op = QKV + (size_t)((nt * 64 + ty * 4 + i) * L_ + l) * 2304 + h * 64 + tx * 4;
    uint2 pk;
    pk.x = pack2(oa[i][0] * inv, oa[i][1] * inv);
    pk.y = pack2(oa[i][2] * inv, oa[i][3] * inv);
    *(uint2*)op = pk;
  }
}

// ---------------------------------------------------------------------------
// s[j] = sum_d (mean_l dec[j,l,d] - emean[j,d])^2
__global__ __launch_bounds__(256) void score_kernel(const float* __restrict__ X,
                                                    const float* __restrict__ em,
                                                    float* __restrict__ Sv) {
  const int j = blockIdx.x;
  const int t = threadIdx.x;
  __shared__ float red[4];
  float part = 0.f;
  for (int c = 0; c < 3; c++) {
    const int d = t + c * 256;
    const float* p = X + (size_t)j * L_ * D_ + d;
    float s = 0.f;
    for (int l = 0; l < L_; l++) s += p[l * D_];
    const float diff = s * (1.f / 64.f) - em[j * D_ + d];
    part += diff * diff;
  }
  const float tot = blockSum256(part, red);
  if (t == 0) Sv[j] = tot;
}

// ---------------------------------------------------------------------------
// prefix argmin per batch over the FIRST n_resp[b] GLOBAL packed scores
// (faithful to reference indexing; stable: strict <). n_ext==1 structurally.
__global__ __launch_bounds__(256) void finalize_kernel(const float* __restrict__ Sv,
                                                       int* __restrict__ mi,
                                                       float* __restrict__ out) {
  const int t = threadIdx.x;
  if (t < B_) {
    const int nr = mi[MI_NRESP + t];
    float best = 3.0e38f; int bi = 0;
    for (int j = 0; j < nr; j++) {
      const float v = Sv[j];
      if (v < best) { best = v; bi = j; }
    }
    mi[MI_NODE + t] = bi + 1;
    int next = nr / 20; if (next < 1) next = 1;   // == floor(nr*0.05) for nr<=39
    out[OUT_NTL + t] = (float)(1 + next);
  }
  if (t == 0) out[OUT_NEA] = 0.f;
  __syncthreads();
  for (int idx = t; idx < B_ * T_; idx += 256) {
    const int b = idx >> 5, tt = idx & 31;
    out[OUT_OH + idx] = (tt == 0 || tt == mi[MI_NODE + b]) ? 1.f : 0.f;
  }
}

// ---------------------------------------------------------------------------
__global__ __launch_bounds__(256) void maskout_kernel(const float* __restrict__ am,
                                                      const int* __restrict__ mi,
                                                      float* __restrict__ out) {
  const int idx = blockIdx.x * 256 + threadIdx.x;   // < 32768
  const int b = idx >> 11, rem = idx & 2047;
  const int tt = rem >> 6, l = rem & 63;
  const int node = mi[MI_NODE + b];
  out[OUT_EXT + idx] = (tt == 0 || tt == node) ? 1.f : 0.f;
  float nm;
  if (tt == 0)      nm = am[(b * T_) * L_ + l];
  else if (tt == 1) nm = am[(b * T_ + node) * L_ + l];
  else              nm = 0.f;
  out[OUT_NMSK + idx] = nm;
}

// ---------------------------------------------------------------------------
__global__ __launch_bounds__(192) void newemb_kernel(const float* __restrict__ emb,
                                                     const int* __restrict__ mi,
                                                     float* __restrict__ out) {
  const int blk = blockIdx.x;                 // b*T*L + t*L + l, 32768 blocks
  const int b = blk >> 11, rem = blk & 2047;
  const int tt = rem >> 6, l = rem & 63;
  const int srct = (tt == 1) ? mi[MI_NODE + b] : 0;
  const float4 v = ((const float4*)(emb + (size_t)((b * T_ + srct) * L_ + l) * D_))[threadIdx.x];
  float* dst = out + OUT_NEMB + (size_t)blk * D_ + threadIdx.x * 4;  // base not 16B-aligned
  dst[0] = v.x; dst[1] = v.y; dst[2] = v.z; dst[3] = v.w;
}

// ===========================================================================
extern "C" void kernel_launch(void* const* d_in, const int* in_sizes, int n_in,
                              void* d_out, int out_size, void* d_ws, size_t ws_size,
                              hipStream_t stream) {
  (void)in_sizes; (void)n_in; (void)out_size; (void)ws_size;
  const int*   tl  = (const int*)d_in[0];
  const float* emb = (const float*)d_in[1];
  const float* am  = (const float*)d_in[2];
  const float* P[28];
  for (int i = 0; i < 28; i++) P[i] = (const float*)d_in[3 + i];
  // P[0..11]=enc{qkv_w,qkv_b,out_w,out_b,ln1_g,ln1_b,w1,c1,w2,c2,ln2_g,ln2_b}
  // P[12..23]=dec{...}; P[24]=pe_w P[25]=pe_b P[26]=pd_w P[27]=pd_b

  float* wsf   = (float*)d_ws;
  int*   mi    = (int*)d_ws;
  float* bias2 = wsf + WS_BIAS2;
  float* emean = wsf + WS_EMEAN;
  float* Sv    = wsf + WS_S;
  unsigned short* BIG = (unsigned short*)(wsf + WS_BIG);  // bf16 QKV / hidden
  float* Zb    = wsf + WS_BIG;                            // fp32 Z overlay
  float* out   = (float*)d_out;
  float* X     = out + OUT_XSCR;   // fp32 residual stream, in d_out scratch

  meta_kernel<<<1, 64, 0, stream>>>(tl, mi);
  gather_kernel<<<NP_ * L_, 192, 0, stream>>>(emb, am, mi, X, bias2);
  emean_kernel<<<NP_, 256, 0, stream>>>(X, emean);

  for (int s = 0; s < 2; s++) {
    const float* const* q = P + s * 12;
    for (int i = 0; i < 2; i++) {
      // QKV projection: X fp32 -> BIG bf16 [rows, 2304]
      gemm_kernel<0, false, 0, 1><<<dim3(NP_, 36), 256, 0, stream>>>(
          X, D_, D_, q[0] + (size_t)i * 3 * D_ * D_, D_, 3 * D_, q[1] + i * 3 * D_,
          BIG, 3 * D_, mi);
      // attention; O (bf16) written into Q columns of BIG
      attn_kernel<<<dim3(8, L_, H_), 256, 0, stream>>>(BIG, bias2, mi);
      // out-proj: O bf16 (lda=2304) -> += X fp32
      gemm_kernel<0, true, 1, 0><<<dim3(NP_, 12), 256, 0, stream>>>(
          BIG, 3 * D_, D_, q[2] + (size_t)i * D_ * D_, D_, D_, q[3] + i * D_,
          X, D_, mi);
      ln_kernel<<<NP_ * L_, 256, 0, stream>>>(X, q[4] + i * D_, q[5] + i * D_, mi);
      // FFN1: X fp32 -> hidden bf16 [rows, 2048] (relu)
      gemm_kernel<1, false, 0, 1><<<dim3(NP_, 32), 256, 0, stream>>>(
          X, D_, D_, q[6] + (size_t)i * F_ * D_, D_, F_, q[7] + i * F_,
          BIG, F_, mi);
      // FFN2: hidden bf16 -> += X fp32
      gemm_kernel<0, true, 1, 0><<<dim3(NP_, 12), 256, 0, stream>>>(
          BIG, F_, F_, q[8] + (size_t)i * D_ * F_, F_, D_, q[9] + i * D_,
          X, D_, mi);
      ln_kernel<<<NP_ * L_, 256, 0, stream>>>(X, q[10] + i * D_, q[11] + i * D_, mi);
    }
    if (s == 0) {
      // z = tanh(h @ pe_w^T + pe_b) into Z fp32 (stride 128, cols 100..127 = 0)
      gemm_kernel<2, false, 0, 0><<<dim3(NP_, 2), 256, 0, stream>>>(
          X, D_, D_, P[24], D_, ZR_, P[25], Zb, ZP_, mi);
      // zd = tanh(z @ pd_w^T + pd_b) into X (decoder input)
      gemm_kernel<2, false, 0, 0><<<dim3(NP_, 12), 256, 0, stream>>>(
          Zb, ZP_, ZP_, P[26], ZR_, D_, P[27], X, D_, mi);
    }
  }

  score_kernel<<<NP_, 256, 0, stream>>>(X, emean, Sv);
  finalize_kernel<<<1, 256, 0, stream>>>(Sv, mi, out);
  maskout_kernel<<<128, 256, 0, stream>>>(am, mi, out);
  newemb_kernel<<<B_ * T_ * L_, 192, 0, stream>>>(emb, mi, out);
}

// Round 3
// 5284.481 us; speedup vs baseline: 3.9915x; 3.9915x over previous
//
#include <hip/hip_runtime.h>
#include <hip/hip_bf16.h>
#include <math.h>

// ============================================================================
// ResponseFilter — round 2: MFMA bf16 GEMMs (m97 pattern).
//
// Round-1 counters: VALUBusy 64%, MfmaUtil 0, HBM 11% -> fp32-vector-pipe
// bound. This round moves QKV/out-proj/FFN1/FFN2 (~1.04 TF) to
// mfma_f32_16x16x32_bf16 with 128x128 tiles + global_load_lds(16B) staging.
// LDS k-group XOR swizzle (kg = slot ^ ((row>>1)&3)) -> 2-way ds_read_b128
// bank aliasing (free) while preserving the wave-uniform-base LDS-DMA layout.
//
// Memory plan (ws budget ~156 MB; 152.7 MB fit in round 1, 421 MB faulted):
//   - residual X: bf16, in d_out new_emb scratch (50.3 MB, dead at epilogue)
//   - weights: converted fp32->bf16 per-dispatch into Wstage (3.54 MB, reused)
//   - BIG: bf16 QKV [32768x2304] (151 MB), hidden [32768x2048] overlaid;
//     attn output O aliases Q columns (race-free); Z fp32 overlay between
//     stacks. pe/pd GEMMs (ragged K/N, ~10 GF) stay on the VALU kernel.
// LN/softmax/score statistics fp32 -> argmin ordering preserved.
// ============================================================================

#define B_  16
#define T_  32
#define L_  64
#define D_  768
#define H_  12
#define F_  2048
#define ZR_ 100
#define ZP_ 128
#define NP_ 512
#define EPS_ 1e-5f

// meta int offsets (d_ws as int*)
#define MI_NTOT  0
#define MI_NRESP 8
#define MI_OFF   32
#define MI_BIDX  64
#define MI_TIDX  576
#define MI_NODE  1088

// ws float offsets
#define WS_BIAS2 2048
#define WS_EMEAN 34816
#define WS_S     428032
#define WS_WST   428544    // bf16 weight stage, 1,769,472 ushorts (3.54 MB)
#define WS_BIG   1313280   // bf16 QKV/hidden region; fp32 Z overlay

// d_out float offsets (flat tuple: oh[512], ext_mask[32768], n_ext_adv[1],
// new_tree_lens[16], new_emb[25165824], new_msk[32768])
#define OUT_OH   0
#define OUT_EXT  512
#define OUT_NEA  33280
#define OUT_NTL  33281
#define OUT_NEMB 33297
#define OUT_NMSK 25199121
#define OUT_XSCR 33300   // bf16 X scratch (16B aligned), 32768*768 ushorts

typedef __attribute__((ext_vector_type(8))) short short8;
typedef __attribute__((ext_vector_type(4))) float f32x4;

__device__ inline float bf2f(unsigned s) {
  return __uint_as_float((s & 0xffffu) << 16);
}
__device__ inline unsigned short f2bf(float x) {
  unsigned u = __float_as_uint(x);
  u += 0x7fffu + ((u >> 16) & 1u);      // round-to-nearest-even
  return (unsigned short)(u >> 16);
}
__device__ inline unsigned pack2(float a, float b) {
  return (unsigned)f2bf(a) | ((unsigned)f2bf(b) << 16);
}

// ---------------------------------------------------------------------------
__global__ void meta_kernel(const int* __restrict__ tl, int* __restrict__ mi) {
  if (threadIdx.x != 0) return;
  int off = 0;
  for (int b = 0; b < B_; b++) {
    int nr = tl[b] - 1;
    mi[MI_NRESP + b] = nr;
    mi[MI_OFF + b] = off;
    off += nr;
  }
  mi[MI_NTOT] = off;
  for (int j = 0; j < NP_; j++) {
    int b = -1, t = 0;
    if (j < off) {
      b = 0;
      while (b + 1 < B_ && j >= mi[MI_OFF + b + 1]) b++;
      t = j - mi[MI_OFF + b] + 1;
    }
    mi[MI_BIDX + j] = b;
    mi[MI_TIDX + j] = t;
  }
}

// ---------------------------------------------------------------------------
// fp32 -> bf16 weight conversion (n multiple of 1024)
__global__ __launch_bounds__(256) void w2bf_kernel(const float* __restrict__ W,
                                                   unsigned short* __restrict__ o) {
  const int i = (blockIdx.x * 256 + threadIdx.x) * 4;
  float4 v = *(const float4*)(W + i);
  uint2 pk; pk.x = pack2(v.x, v.y); pk.y = pack2(v.z, v.w);
  *(uint2*)(o + i) = pk;
}

// ---------------------------------------------------------------------------
// X[j,l,:] bf16 = reply embedding (zero for padded j); bias2 = mask or -1e30
__global__ __launch_bounds__(192) void gather_kernel(
    const float* __restrict__ emb, const float* __restrict__ am,
    const int* __restrict__ mi, unsigned short* __restrict__ X,
    float* __restrict__ bias2) {
  const int blk = blockIdx.x;          // j*64 + l
  const int j = blk >> 6, l = blk & 63;
  const int ntot = mi[MI_NTOT];
  const int t = threadIdx.x;
  float4 v = make_float4(0.f, 0.f, 0.f, 0.f);
  if (j < ntot) {
    const int b = mi[MI_BIDX + j], tt = mi[MI_TIDX + j];
    v = ((const float4*)(emb + (size_t)((b * T_ + tt) * L_ + l) * D_))[t];
    if (t == 0) bias2[blk] = am[(b * T_ + tt) * L_ + l];
  } else {
    if (t == 0) bias2[blk] = -1e30f;
  }
  uint2 pk; pk.x = pack2(v.x, v.y); pk.y = pack2(v.z, v.w);
  *(uint2*)(X + (size_t)blk * D_ + t * 4) = pk;
}

// ---------------------------------------------------------------------------
__global__ __launch_bounds__(256) void emean_kernel(const unsigned short* __restrict__ X,
                                                    float* __restrict__ em) {
  const int j = blockIdx.x;
  int d = threadIdx.x;
  for (int c = 0; c < 3; c++, d += 256) {
    const unsigned short* p = X + (size_t)j * L_ * D_ + d;
    float s = 0.f;
    for (int l = 0; l < L_; l++) s += bf2f(p[l * D_]);
    em[j * D_ + d] = s * (1.f / 64.f);
  }
}

// ---------------------------------------------------------------------------
__device__ inline float blockSum256(float v, float* red) {
  #pragma unroll
  for (int o = 32; o > 0; o >>= 1) v += __shfl_down(v, o);
  const int lane = threadIdx.x & 63, wid = threadIdx.x >> 6;
  __syncthreads();
  if (lane == 0) red[wid] = v;
  __syncthreads();
  return red[0] + red[1] + red[2] + red[3];
}

// in-place LN (bf16 storage, fp32 stats); skips padded rows
__global__ __launch_bounds__(256) void ln_kernel(unsigned short* __restrict__ X,
                                                 const float* __restrict__ g,
                                                 const float* __restrict__ bb,
                                                 const int* __restrict__ mi) {
  const int row = blockIdx.x;
  if (row >= mi[MI_NTOT] * L_) return;
  unsigned short* p = X + (size_t)row * D_;
  const int t = threadIdx.x;
  __shared__ float red[4];
  float v0 = bf2f(p[t]), v1 = bf2f(p[t + 256]), v2 = bf2f(p[t + 512]);
  float s = blockSum256(v0 + v1 + v2, red);
  float m = s * (1.f / 768.f);
  float d0 = v0 - m, d1 = v1 - m, d2 = v2 - m;
  float q = blockSum256(d0 * d0 + d1 * d1 + d2 * d2, red);
  float r = rsqrtf(q * (1.f / 768.f) + EPS_);
  p[t]       = f2bf(d0 * r * g[t]       + bb[t]);
  p[t + 256] = f2bf(d1 * r * g[t + 256] + bb[t + 256]);
  p[t + 512] = f2bf(d2 * r * g[t + 512] + bb[t + 512]);
}

// ---------------------------------------------------------------------------
// MFMA bf16 GEMM: C[M,N] = [C +] act(A @ W^T + bias). 128x128 tile, 256 thr
// (4 waves 2x2, each 64x64 via 4x4 of 16x16x32 MFMA). K mult of 32, N mult
// of 128. global_load_lds 16B staging with k-group XOR swizzle:
//   LDS slot (row, sp) holds kg = sp ^ ((row>>1)&3)  -> ds_read_b128 2-way.
template <int ACT, bool ADD>
__global__ __launch_bounds__(256) void gemm_mfma(
    const unsigned short* __restrict__ A, int lda, int K,
    const unsigned short* __restrict__ W, int ldw,
    const float* __restrict__ bias,
    unsigned short* __restrict__ C, int ldc,
    const int* __restrict__ mi) {
  const int rows = mi[MI_NTOT] * 64;
  const int row0 = blockIdx.x * 128;
  if (row0 >= rows) return;
  const int col0 = blockIdx.y * 128;
  __shared__ unsigned short As[128 * 32];
  __shared__ unsigned short Bs[128 * 32];
  const int t = threadIdx.x;
  const int lane = t & 63, w = t >> 6;
  const int wr = w >> 1, wc = w & 1;
  const int quad = lane >> 4, l15 = lane & 15;
  f32x4 acc[4][4];
  #pragma unroll
  for (int i = 0; i < 4; i++)
    #pragma unroll
    for (int j = 0; j < 4; j++) acc[i][j] = (f32x4){0.f, 0.f, 0.f, 0.f};

  // per-lane staging coords (2 chunks per wave per tile)
  int srow[2], skg[2], schunk[2];
  #pragma unroll
  for (int r = 0; r < 2; r++) {
    const int c = r * 4 + w;
    const int g = c * 64 + lane;
    const int row = g >> 2, slot = g & 3;
    schunk[r] = c;
    srow[r] = row;
    skg[r] = slot ^ ((row >> 1) & 3);
  }
  // fragment LDS offsets (ushorts)
  int aoff[4], boff[4];
  #pragma unroll
  for (int m = 0; m < 4; m++) {
    const int ar = wr * 64 + m * 16 + l15;
    aoff[m] = ar * 32 + (quad ^ ((ar >> 1) & 3)) * 8;
    const int bn = wc * 64 + m * 16 + l15;
    boff[m] = bn * 32 + (quad ^ ((bn >> 1) & 3)) * 8;
  }

  for (int k0 = 0; k0 < K; k0 += 32) {
    #pragma unroll
    for (int r = 0; r < 2; r++) {
      const unsigned short* ga = A + (size_t)(row0 + srow[r]) * lda + k0 + skg[r] * 8;
      __builtin_amdgcn_global_load_lds(
          (const __attribute__((address_space(1))) void*)ga,
          (__attribute__((address_space(3))) void*)(As + schunk[r] * 512), 16, 0, 0);
      const unsigned short* gb = W + (size_t)(col0 + srow[r]) * ldw + k0 + skg[r] * 8;
      __builtin_amdgcn_global_load_lds(
          (const __attribute__((address_space(1))) void*)gb,
          (__attribute__((address_space(3))) void*)(Bs + schunk[r] * 512), 16, 0, 0);
    }
    __syncthreads();
    short8 af[4], bfr[4];
    #pragma unroll
    for (int m = 0; m < 4; m++) {
      af[m]  = *(const short8*)(As + aoff[m]);
      bfr[m] = *(const short8*)(Bs + boff[m]);
    }
    #pragma unroll
    for (int m = 0; m < 4; m++)
      #pragma unroll
      for (int n = 0; n < 4; n++)
        acc[m][n] = __builtin_amdgcn_mfma_f32_16x16x32_bf16(af[m], bfr[n], acc[m][n], 0, 0, 0);
    __syncthreads();
  }

  // epilogue: C/D layout col = lane&15, row = quad*4 + reg
  float bv[4];
  #pragma unroll
  for (int n = 0; n < 4; n++) bv[n] = bias[col0 + wc * 64 + n * 16 + l15];
  #pragma unroll
  for (int m = 0; m < 4; m++) {
    #pragma unroll
    for (int reg = 0; reg < 4; reg++) {
      const size_t cr = (size_t)(row0 + wr * 64 + m * 16 + quad * 4 + reg) * ldc;
      #pragma unroll
      for (int n = 0; n < 4; n++) {
        const int cn = col0 + wc * 64 + n * 16 + l15;
        float x = acc[m][n][reg] + bv[n];
        if (ACT == 1) x = fmaxf(x, 0.f);
        if (ADD) x += bf2f(C[cr + cn]);
        C[cr + cn] = f2bf(x);
      }
    }
  }
}

// ---------------------------------------------------------------------------
// VALU GEMM (kept for ragged pe/pd only): C = act(A @ W^T + b)
// AT: 0 fp32 A, 1 bf16 A.  CT: 0 fp32 C, 1 bf16 C.
template <int ACT, int AT, int CT>
__global__ __launch_bounds__(256) void gemm_kernel(
    const void* __restrict__ Av, int lda, int kloop,
    const float* __restrict__ W, int kw, int nreal,
    const float* __restrict__ bias,
    void* __restrict__ Cv, int ldc,
    const int* __restrict__ mi) {
  if ((int)blockIdx.x >= mi[MI_NTOT]) return;
  __shared__ float As[16][68];
  __shared__ float Ws[16][68];
  const int t = threadIdx.x;
  const int tx = t & 15, ty = t >> 4;
  const int lrow = t >> 2, lkg = (t & 3) * 4;
  const size_t row0 = (size_t)blockIdx.x * 64;
  const int col0 = blockIdx.y * 64;
  float acc[4][4] = {};
  for (int k0 = 0; k0 < kloop; k0 += 16) {
    float a4[4];
    if (AT == 0) {
      float4 av = *(const float4*)((const float*)Av + (row0 + lrow) * (size_t)lda + k0 + lkg);
      a4[0] = av.x; a4[1] = av.y; a4[2] = av.z; a4[3] = av.w;
    } else {
      uint2 u = *(const uint2*)((const unsigned short*)Av + (row0 + lrow) * (size_t)lda + k0 + lkg);
      a4[0] = bf2f(u.x); a4[1] = bf2f(u.x >> 16);
      a4[2] = bf2f(u.y); a4[3] = bf2f(u.y >> 16);
    }
    float wv[4];
    const int wn = col0 + lrow;
    #pragma unroll
    for (int i = 0; i < 4; i++) {
      const int k = k0 + lkg + i;
      wv[i] = (wn < nreal && k < kw) ? W[(size_t)wn * kw + k] : 0.f;
    }
    __syncthreads();
    As[lkg + 0][lrow] = a4[0]; As[lkg + 1][lrow] = a4[1];
    As[lkg + 2][lrow] = a4[2]; As[lkg + 3][lrow] = a4[3];
    Ws[lkg + 0][lrow] = wv[0]; Ws[lkg + 1][lrow] = wv[1];
    Ws[lkg + 2][lrow] = wv[2]; Ws[lkg + 3][lrow] = wv[3];
    __syncthreads();
    #pragma unroll
    for (int kk = 0; kk < 16; kk++) {
      float4 av4 = *(const float4*)(&As[kk][ty * 4]);
      float4 wv4 = *(const float4*)(&Ws[kk][tx * 4]);
      float aa[4] = {av4.x, av4.y, av4.z, av4.w};
      float ww[4] = {wv4.x, wv4.y, wv4.z, wv4.w};
      #pragma unroll
      for (int i = 0; i < 4; i++)
        #pragma unroll
        for (int j = 0; j < 4; j++) acc[i][j] += aa[i] * ww[j];
    }
  }
  const int n0 = col0 + tx * 4;
  float bv[4];
  #pragma unroll
  for (int j = 0; j < 4; j++) bv[j] = (n0 + j < nreal) ? bias[n0 + j] : 0.f;
  #pragma unroll
  for (int i = 0; i < 4; i++) {
    float v[4];
    #pragma unroll
    for (int j = 0; j < 4; j++) {
      float x = acc[i][j] + bv[j];
      if (ACT == 1) x = fmaxf(x, 0.f);
      if (ACT == 2) x = tanhf(x);
      v[j] = x;
    }
    if (CT == 0) {
      float* cp = (float*)Cv + (row0 + ty * 4 + i) * (size_t)ldc + n0;
      *(float4*)cp = make_float4(v[0], v[1], v[2], v[3]);
    } else {
      unsigned short* cp = (unsigned short*)Cv + (row0 + ty * 4 + i) * (size_t)ldc + n0;
      uint2 pk; pk.x = pack2(v[0], v[1]); pk.y = pack2(v[2], v[3]);
      *(uint2*)cp = pk;
    }
  }
}

// ---------------------------------------------------------------------------
// Attention over the response dim per (l, h); flash-style online softmax.
// QKV bf16 (stride 2304); O bf16 written into Q columns (race-free aliasing).
__global__ __launch_bounds__(256) void attn_kernel(
    unsigned short* __restrict__ QKV, const float* __restrict__ bias2,
    const int* __restrict__ mi) {
  const int ntot = mi[MI_NTOT];
  const int nt = blockIdx.x, l = blockIdx.y, h = blockIdx.z;
  if (nt * 64 >= ntot) return;
  __shared__ float Qs[64][68];
  __shared__ float KVs[64][68];
  __shared__ float Ps[64][68];
  const int t = threadIdx.x;
  const int tx = t & 15, ty = t >> 4;
  const int lrow = t >> 2, lf = (t & 3) * 4;
  #pragma unroll
  for (int c = 0; c < 4; c++) {
    const int d0 = lf + c * 16;
    uint2 q = *(const uint2*)(QKV + (size_t)((nt * 64 + lrow) * L_ + l) * 2304 + h * 64 + d0);
    Qs[d0 + 0][lrow] = bf2f(q.x); Qs[d0 + 1][lrow] = bf2f(q.x >> 16);
    Qs[d0 + 2][lrow] = bf2f(q.y); Qs[d0 + 3][lrow] = bf2f(q.y >> 16);
  }
  float runmax[4], runsum[4], oa[4][4];
  #pragma unroll
  for (int i = 0; i < 4; i++) {
    runmax[i] = -3.0e38f; runsum[i] = 0.f;
    #pragma unroll
    for (int j = 0; j < 4; j++) oa[i][j] = 0.f;
  }
  __syncthreads();
  for (int mt = 0; mt < 8; mt++) {
    #pragma unroll
    for (int c = 0; c < 4; c++) {
      const int d0 = lf + c * 16;
      uint2 k = *(const uint2*)(QKV + (size_t)((mt * 64 + lrow) * L_ + l) * 2304 + 768 + h * 64 + d0);
      KVs[d0 + 0][lrow] = bf2f(k.x); KVs[d0 + 1][lrow] = bf2f(k.x >> 16);
      KVs[d0 + 2][lrow] = bf2f(k.y); KVs[d0 + 3][lrow] = bf2f(k.y >> 16);
    }
    __syncthreads();
    float sv[4][4] = {};
    #pragma unroll 8
    for (int kk = 0; kk < 64; kk++) {
      float4 q4 = *(const float4*)(&Qs[kk][ty * 4]);
      float4 k4 = *(const float4*)(&KVs[kk][tx * 4]);
      float qa[4] = {q4.x, q4.y, q4.z, q4.w};
      float ka[4] = {k4.x, k4.y, k4.z, k4.w};
      #pragma unroll
      for (int i = 0; i < 4; i++)
        #pragma unroll
        for (int j = 0; j < 4; j++) sv[i][j] += qa[i] * ka[j];
    }
    float bj[4];
    #pragma unroll
    for (int j = 0; j < 4; j++) bj[j] = bias2[(mt * 64 + tx * 4 + j) * 64 + l];
    float tmax[4], tsum[4];
    #pragma unroll
    for (int i = 0; i < 4; i++) {
      #pragma unroll
      for (int j = 0; j < 4; j++) sv[i][j] = sv[i][j] * 0.125f + bj[j];
      tmax[i] = fmaxf(fmaxf(sv[i][0], sv[i][1]), fmaxf(sv[i][2], sv[i][3]));
    }
    #pragma unroll
    for (int o2 = 1; o2 < 16; o2 <<= 1)
      #pragma unroll
      for (int i = 0; i < 4; i++) tmax[i] = fmaxf(tmax[i], __shfl_xor(tmax[i], o2));
    #pragma unroll
    for (int i = 0; i < 4; i++) {
      const float nmax = fmaxf(runmax[i], tmax[i]);
      const float alpha = __expf(runmax[i] - nmax);
      runmax[i] = nmax;
      float s0 = 0.f;
      #pragma unroll
      for (int j = 0; j < 4; j++) { sv[i][j] = __expf(sv[i][j] - nmax); s0 += sv[i][j]; }
      tsum[i] = s0;
      #pragma unroll
      for (int j = 0; j < 4; j++) oa[i][j] *= alpha;
      runsum[i] *= alpha;
    }
    #pragma unroll
    for (int o2 = 1; o2 < 16; o2 <<= 1)
      #pragma unroll
      for (int i = 0; i < 4; i++) tsum[i] += __shfl_xor(tsum[i], o2);
    #pragma unroll
    for (int i = 0; i < 4; i++) runsum[i] += tsum[i];
    __syncthreads();
    #pragma unroll
    for (int i = 0; i < 4; i++)
      *(float4*)(&Ps[ty * 4 + i][tx * 4]) = make_float4(sv[i][0], sv[i][1], sv[i][2], sv[i][3]);
    #pragma unroll
    for (int c = 0; c < 4; c++) {
      const int d0 = lf + c * 16;
      uint2 v = *(const uint2*)(QKV + (size_t)((mt * 64 + lrow) * L_ + l) * 2304 + 1536 + h * 64 + d0);
      KVs[lrow][d0 + 0] = bf2f(v.x); KVs[lrow][d0 + 1] = bf2f(v.x >> 16);
      KVs[lrow][d0 + 2] = bf2f(v.y); KVs[lrow][d0 + 3] = bf2f(v.y >> 16);
    }
    __syncthreads();
    #pragma unroll 4
    for (int m4 = 0; m4 < 16; m4++) {
      float4 pr[4];
      #pragma unroll
      for (int i = 0; i < 4; i++) pr[i] = *(const float4*)(&Ps[ty * 4 + i][m4 * 4]);
      #pragma unroll
      for (int c = 0; c < 4; c++) {
        float4 v4 = *(const float4*)(&KVs[m4 * 4 + c][tx * 4]);
        float va[4] = {v4.x, v4.y, v4.z, v4.w};
        float pc[4];
        #pragma unroll
        for (int i = 0; i < 4; i++) pc[i] = ((const float*)&pr[i])[c];
        #pragma unroll
        for (int i = 0; i < 4; i++)
          #pragma unroll
          for (int j = 0; j < 4; j++) oa[i][j] += pc[i] * va[j];
      }
    }
    __syncthreads();
  }
  #pragma unroll
  for (int i = 0; i < 4; i++) {
    const float inv = 1.f / runsum[i];
    unsigned short* op = QKV + (size_t)((nt * 64 + ty * 4 + i) * L_ + l) * 2304 + h * 64 + tx * 4;
    uint2 pk;
    pk.x = pack2(oa[i][0] * inv, oa[i][1] * inv);
    pk.y = pack2(oa[i][2] * inv, oa[i][3] * inv);
    *(uint2*)op = pk;
  }
}

// ---------------------------------------------------------------------------
__global__ __launch_bounds__(256) void score_kernel(const unsigned short* __restrict__ X,
                                                    const float* __restrict__ em,
                                                    float* __restrict__ Sv) {
  const int j = blockIdx.x;
  const int t = threadIdx.x;
  __shared__ float red[4];
  float part = 0.f;
  for (int c = 0; c < 3; c++) {
    const int d = t + c * 256;
    const unsigned short* p = X + (size_t)j * L_ * D_ + d;
    float s = 0.f;
    for (int l = 0; l < L_; l++) s += bf2f(p[l * D_]);
    const float diff = s * (1.f / 64.f) - em[j * D_ + d];
    part += diff * diff;
  }
  const float tot = blockSum256(part, red);
  if (t == 0) Sv[j] = tot;
}

// ---------------------------------------------------------------------------
__global__ __launch_bounds__(256) void finalize_kernel(const float* __restrict__ Sv,
                                                       int* __restrict__ mi,
                                                       float* __restrict__ out) {
  const int t = threadIdx.x;
  if (t < B_) {
    const int nr = mi[MI_NRESP + t];
    float best = 3.0e38f; int bi = 0;
    for (int j = 0; j < nr; j++) {
      const float v = Sv[j];
      if (v < best) { best = v; bi = j; }
    }
    mi[MI_NODE + t] = bi + 1;
    int next = nr / 20; if (next < 1) next = 1;
    out[OUT_NTL + t] = (float)(1 + next);
  }
  if (t == 0) out[OUT_NEA] = 0.f;
  __syncthreads();
  for (int idx = t; idx < B_ * T_; idx += 256) {
    const int b = idx >> 5, tt = idx & 31;
    out[OUT_OH + idx] = (tt == 0 || tt == mi[MI_NODE + b]) ? 1.f : 0.f;
  }
}

// ---------------------------------------------------------------------------
__global__ __launch_bounds__(256) void maskout_kernel(const float* __restrict__ am,
                                                      const int* __restrict__ mi,
                                                      float* __restrict__ out) {
  const int idx = blockIdx.x * 256 + threadIdx.x;
  const int b = idx >> 11, rem = idx & 2047;
  const int tt = rem >> 6, l = rem & 63;
  const int node = mi[MI_NODE + b];
  out[OUT_EXT + idx] = (tt == 0 || tt == node) ? 1.f : 0.f;
  float nm;
  if (tt == 0)      nm = am[(b * T_) * L_ + l];
  else if (tt == 1) nm = am[(b * T_ + node) * L_ + l];
  else              nm = 0.f;
  out[OUT_NMSK + idx] = nm;
}

// ---------------------------------------------------------------------------
__global__ __launch_bounds__(192) void newemb_kernel(const float* __restrict__ emb,
                                                     const int* __restrict__ mi,
                                                     float* __restrict__ out) {
  const int blk = blockIdx.x;
  const int b = blk >> 11, rem = blk & 2047;
  const int tt = rem >> 6, l = rem & 63;
  const int srct = (tt == 1) ? mi[MI_NODE + b] : 0;
  const float4 v = ((const float4*)(emb + (size_t)((b * T_ + srct) * L_ + l) * D_))[threadIdx.x];
  float* dst = out + OUT_NEMB + (size_t)blk * D_ + threadIdx.x * 4;
  dst[0] = v.x; dst[1] = v.y; dst[2] = v.z; dst[3] = v.w;
}

// ===========================================================================
extern "C" void kernel_launch(void* const* d_in, const int* in_sizes, int n_in,
                              void* d_out, int out_size, void* d_ws, size_t ws_size,
                              hipStream_t stream) {
  (void)in_sizes; (void)n_in; (void)out_size; (void)ws_size;
  const int*   tl  = (const int*)d_in[0];
  const float* emb = (const float*)d_in[1];
  const float* am  = (const float*)d_in[2];
  const float* P[28];
  for (int i = 0; i < 28; i++) P[i] = (const float*)d_in[3 + i];

  float* wsf   = (float*)d_ws;
  int*   mi    = (int*)d_ws;
  float* bias2 = wsf + WS_BIAS2;
  float* emean = wsf + WS_EMEAN;
  float* Sv    = wsf + WS_S;
  unsigned short* Wst = (unsigned short*)(wsf + WS_WST);
  unsigned short* BIG = (unsigned short*)(wsf + WS_BIG);
  float* Zb    = wsf + WS_BIG;                      // fp32 Z overlay (enc->dec)
  float* out   = (float*)d_out;
  unsigned short* X = (unsigned short*)(out + OUT_XSCR);  // bf16 residual

  meta_kernel<<<1, 64, 0, stream>>>(tl, mi);
  gather_kernel<<<NP_ * L_, 192, 0, stream>>>(emb, am, mi, X, bias2);
  emean_kernel<<<NP_, 256, 0, stream>>>(X, emean);

  const int RT = NP_ * 64 / 128;   // 256 row tiles
  for (int s = 0; s < 2; s++) {
    const float* const* q = P + s * 12;
    for (int i = 0; i < 2; i++) {
      // QKV: X -> BIG [rows, 2304]
      w2bf_kernel<<<(3 * D_ * D_) / 1024, 256, 0, stream>>>(q[0] + (size_t)i * 3 * D_ * D_, Wst);
      gemm_mfma<0, false><<<dim3(RT, 18), 256, 0, stream>>>(
          X, D_, D_, Wst, D_, q[1] + i * 3 * D_, BIG, 3 * D_, mi);
      attn_kernel<<<dim3(8, L_, H_), 256, 0, stream>>>(BIG, bias2, mi);
      // out-proj: O (Q cols of BIG, lda=2304) -> += X
      w2bf_kernel<<<(D_ * D_) / 1024, 256, 0, stream>>>(q[2] + (size_t)i * D_ * D_, Wst);
      gemm_mfma<0, true><<<dim3(RT, 6), 256, 0, stream>>>(
          BIG, 3 * D_, D_, Wst, D_, q[3] + i * D_, X, D_, mi);
      ln_kernel<<<NP_ * L_, 256, 0, stream>>>(X, q[4] + i * D_, q[5] + i * D_, mi);
      // FFN1: X -> hidden BIG [rows, 2048] (relu)
      w2bf_kernel<<<(F_ * D_) / 1024, 256, 0, stream>>>(q[6] + (size_t)i * F_ * D_, Wst);
      gemm_mfma<1, false><<<dim3(RT, 16), 256, 0, stream>>>(
          X, D_, D_, Wst, D_, q[7] + i * F_, BIG, F_, mi);
      // FFN2: hidden -> += X
      w2bf_kernel<<<(D_ * F_) / 1024, 256, 0, stream>>>(q[8] + (size_t)i * D_ * F_, Wst);
      gemm_mfma<0, true><<<dim3(RT, 6), 256, 0, stream>>>(
          BIG, F_, F_, Wst, F_, q[9] + i * D_, X, D_, mi);
      ln_kernel<<<NP_ * L_, 256, 0, stream>>>(X, q[10] + i * D_, q[11] + i * D_, mi);
    }
    if (s == 0) {
      // z = tanh(h @ pe_w^T + pe_b) -> Z fp32 (stride 128, cols 100..127 = 0)
      gemm_kernel<2, 1, 0><<<dim3(NP_, 2), 256, 0, stream>>>(
          X, D_, D_, P[24], D_, ZR_, P[25], Zb, ZP_, mi);
      // zd = tanh(z @ pd_w^T + pd_b) -> X bf16 (decoder input)
      gemm_kernel<2, 0, 1><<<dim3(NP_, 12), 256, 0, stream>>>(
          Zb, ZP_, ZP_, P[26], ZR_, D_, P[27], X, D_, mi);
    }
  }

  score_kernel<<<NP_, 256, 0, stream>>>(X, emean, Sv);
  finalize_kernel<<<1, 256, 0, stream>>>(Sv, mi, out);
  maskout_kernel<<<128, 256, 0, stream>>>(am, mi, out);
  newemb_kernel<<<B_ * T_ * L_, 192, 0, stream>>>(emb, mi, out);
}